// Round 3
// baseline (16958.482 us; speedup 1.0000x reference)
//
#include <hip/hip_runtime.h>
#include <stdint.h>

typedef unsigned long long u64t;

__device__ __forceinline__ float sigf(float x) { return 1.f / (1.f + __expf(-x)); }
__device__ __forceinline__ float tanhf_s(float x) {
    float ax = fabsf(x);
    float t = __expf(-2.f * ax);
    float r = (1.f - t) / (1.f + t);
    return copysignf(r, x);
}

// ---------------------------------------------------------------------------
// K1: char LSTM, register-weight version.
// 512 blocks x 256 thr, 16 words/block sequentially.
// Thread t owns gate row t (gate g=t>>6, elem e=t&63): Wih row + Whh row in
// 128 VGPRs. Per step: 64+64 dot, gates through LDS, g==0 does cell update.
// ---------------------------------------------------------------------------
__global__ __launch_bounds__(256) void k_char_lstm(
    const int* __restrict__ chars, const float* __restrict__ char_emb,
    const float* __restrict__ Wih, const float* __restrict__ Whh,
    const float* __restrict__ bih, const float* __restrict__ bhh,
    float* __restrict__ h_char, int words_per_block)
{
    __shared__ float X[768];    // 12 steps x 64
    __shared__ float gl[256];   // activated gates [g][e]
    __shared__ float hl[64];    // current h
    const int t = threadIdx.x;
    const int g = t >> 6, e = t & 63;

    float wih[64], whh[64];
    {
        const float4* p1 = (const float4*)(Wih + t * 64);
        const float4* p2 = (const float4*)(Whh + t * 64);
#pragma unroll
        for (int q = 0; q < 16; ++q) {
            float4 a = p1[q];
            wih[4*q+0] = a.x; wih[4*q+1] = a.y; wih[4*q+2] = a.z; wih[4*q+3] = a.w;
        }
#pragma unroll
        for (int q = 0; q < 16; ++q) {
            float4 b = p2[q];
            whh[4*q+0] = b.x; whh[4*q+1] = b.y; whh[4*q+2] = b.z; whh[4*q+3] = b.w;
        }
    }
    const float bias = bih[t] + bhh[t];

    for (int wi = 0; wi < words_per_block; ++wi) {
        const int w = blockIdx.x * words_per_block + wi;
        const int* crow = chars + w * 12;
        for (int q = t; q < 768; q += 256)
            X[q] = char_emb[crow[q >> 6] * 64 + (q & 63)];
        if (t < 64) hl[t] = 0.f;
        __syncthreads();

        float c = 0.f, hreg = 0.f;
        for (int st = 0; st < 12; ++st) {
            float s_ = bias;
            const float4* xv4 = (const float4*)(X + st * 64);
            const float4* hv4 = (const float4*)hl;
#pragma unroll
            for (int q = 0; q < 16; ++q) {
                float4 x4 = xv4[q];
                s_ += wih[4*q+0]*x4.x + wih[4*q+1]*x4.y + wih[4*q+2]*x4.z + wih[4*q+3]*x4.w;
            }
#pragma unroll
            for (int q = 0; q < 16; ++q) {
                float4 h4 = hv4[q];
                s_ += whh[4*q+0]*h4.x + whh[4*q+1]*h4.y + whh[4*q+2]*h4.z + whh[4*q+3]*h4.w;
            }
            gl[t] = (g == 2) ? tanhf_s(s_) : sigf(s_);
            __syncthreads();          // gates visible
            if (g == 0) {
                float ii = gl[e], ff = gl[64 + e], gg = gl[128 + e], oo = gl[192 + e];
                c = ff * c + ii * gg;
                hreg = oo * tanhf_s(c);
                hl[e] = hreg;
            }
            __syncthreads();          // h visible; gl safe to rewrite
        }
        if (g == 0) h_char[w * 64 + e] = hreg;
    }
}

// ---------------------------------------------------------------------------
// K2: materialize X[w][0:256]=word_emb[sent[w]], X[w][256:320]=h_char[w]. f32.
// One block (320 thr = 5 waves) per word.
// ---------------------------------------------------------------------------
__global__ __launch_bounds__(320) void k_build_x(
    const int* __restrict__ sentence, const float* __restrict__ word_emb,
    const float* __restrict__ h_char, float* __restrict__ X)
{
    const int w = blockIdx.x, t = threadIdx.x;
    float v;
    if (t < 256) v = word_emb[(size_t)sentence[w] * 256 + t];
    else         v = h_char[(size_t)w * 64 + (t - 256)];
    X[(size_t)w * 320 + t] = v;
}

// ---------------------------------------------------------------------------
// K3: pack W_out [64][512] -> WP with WP[k4*256 + j*4 + c] = W_out[j][k4*4+c]
// ---------------------------------------------------------------------------
__global__ __launch_bounds__(256) void k_pack_wout(const float* __restrict__ W_out, float* __restrict__ WP)
{
    int i = blockIdx.x * 256 + threadIdx.x;  // < 32768
    int c = i & 3, j = (i >> 2) & 63, k4 = i >> 8;
    WP[i] = W_out[j * 512 + k4 * 4 + c];
}

// ---------------------------------------------------------------------------
// K4: persistent word LSTM, fully f32. 64 WGs x 256 thr.
// WG owns 8 h-elems, 32 gate rows. Thread: row rw=t>>3 (g=rw>>3,e=rw&7),
// k-slice ks=t&7. Weights in VGPRs: Whh[grow][ks*64..+64) (64) and
// Wih[grow][ks*40..+40) (40). Per step: xdot (no h dep, hidden under poll),
// poll h_{s-1}, hdot, 8-lane reduce, gates, cell update, publish.
// h exchange: DOUBLE-BUFFERED Hpub[2][512] u64 = (tag<<32)|f32bits.
// Poll slot s&1 for tag==s; publish to slot (s+1)&1 with tag s+1. A slot is
// only rewritten with tag s+2 after ALL WGs published s+1, which requires
// every WG to have consumed tag s -> no overtaking deadlock.
// ---------------------------------------------------------------------------
__global__ __launch_bounds__(256) void k_word_lstm(
    const float* __restrict__ Whh, const float* __restrict__ Wih,
    const float* __restrict__ X,
    const float* __restrict__ bih, const float* __restrict__ bhh,
    u64t* Hpub, float* __restrict__ ys)
{
    __shared__ float h_lds[544];
    __shared__ float g_lds[32];
    const int t = threadIdx.x, wg = blockIdx.x;
    const int rw = t >> 3, ks = t & 7;
    const int g = rw >> 3, e = rw & 7;
    const int grow = g * 512 + wg * 8 + e;

    float whhr[64];
    {
        const float4* wsrc = (const float4*)(Whh + (size_t)grow * 512 + ks * 64);
#pragma unroll
        for (int j = 0; j < 16; ++j) {
            float4 v = wsrc[j];
            whhr[4*j] = v.x; whhr[4*j+1] = v.y; whhr[4*j+2] = v.z; whhr[4*j+3] = v.w;
        }
    }
    float wihr[40];
    {
        const float4* wsrc = (const float4*)(Wih + (size_t)grow * 320 + ks * 40);
#pragma unroll
        for (int j = 0; j < 10; ++j) {
            float4 v = wsrc[j];
            wihr[4*j] = v.x; wihr[4*j+1] = v.y; wihr[4*j+2] = v.z; wihr[4*j+3] = v.w;
        }
    }
    const float bias = bih[grow] + bhh[grow];

    const int lidx1 = t + ((t >> 6) << 2);
    const int lidx2 = (t + 256) + (((t + 256) >> 6) << 2);
    const float* hb = h_lds + ks * 68;
    float c = 0.f;

    for (int s = 0; s < 8192; ++s) {
        // ---- pre-poll: x contribution (independent of h_{s-1}) ----
        float x0 = 0.f, x1 = 0.f, x2 = 0.f, x3 = 0.f;
        {
            const float4* xr = (const float4*)(X + (size_t)s * 320 + ks * 40);
#pragma unroll
            for (int q = 0; q < 10; ++q) {
                float4 xv = xr[q];
                x0 += wihr[4*q]   * xv.x;
                x1 += wihr[4*q+1] * xv.y;
                x2 += wihr[4*q+2] * xv.z;
                x3 += wihr[4*q+3] * xv.w;
            }
        }

        // ---- poll for h_{s-1} ----
        const u64t want = (u64t)s;
        u64t* slot = Hpub + ((s & 1) << 9);
        u64t v1 = 0, v2 = 0;
        bool d1 = false, d2 = false;
        int spin = 0;
        do {
            if (!d1) { v1 = __hip_atomic_load(slot + t,       __ATOMIC_RELAXED, __HIP_MEMORY_SCOPE_AGENT); d1 = ((v1 >> 32) == want); }
            if (!d2) { v2 = __hip_atomic_load(slot + t + 256, __ATOMIC_RELAXED, __HIP_MEMORY_SCOPE_AGENT); d2 = ((v2 >> 32) == want); }
        } while (!(d1 && d2) && ++spin < (1 << 26));  // bounded: never hang the container
        h_lds[lidx1] = __uint_as_float((unsigned)v1);
        h_lds[lidx2] = __uint_as_float((unsigned)v2);
        __syncthreads();

        // ---- h contribution ----
        float s0 = x0, s1 = x1, s2 = x2, s3 = x3;
#pragma unroll
        for (int q = 0; q < 16; ++q) {
            float4 hv = *(const float4*)(hb + 4 * q);
            s0 += whhr[4*q]   * hv.x;
            s1 += whhr[4*q+1] * hv.y;
            s2 += whhr[4*q+2] * hv.z;
            s3 += whhr[4*q+3] * hv.w;
        }
        float sum = (s0 + s1) + (s2 + s3);
        sum += __shfl_xor(sum, 1);
        sum += __shfl_xor(sum, 2);
        sum += __shfl_xor(sum, 4);
        if (ks == 0) {
            float gate = sum + bias;
            g_lds[rw] = (g == 2) ? tanhf_s(gate) : sigf(gate);
        }
        __syncthreads();
        if (t < 8) {
            float ii = g_lds[t], ff = g_lds[8 + t], gg = g_lds[16 + t], oo = g_lds[24 + t];
            c = ff * c + ii * gg;
            float h = oo * tanhf_s(c);
            ys[(size_t)s * 512 + wg * 8 + t] = h;
            u64t pv = ((u64t)(s + 1) << 32) | (u64t)__float_as_uint(h);
            __hip_atomic_store(Hpub + (((s + 1) & 1) << 9) + wg * 8 + t, pv,
                               __ATOMIC_RELAXED, __HIP_MEMORY_SCOPE_AGENT);
        }
        // g_lds rewrite only after next iter's barrier 1 (writers must pass it,
        // which requires t<8 readers done); h_lds rewrite gated by barrier 2.
    }
}

// ---------------------------------------------------------------------------
// K5: logits = ys @ W_out.T + b_out, log_softmax per row. 4 rows/block.
// ---------------------------------------------------------------------------
__global__ __launch_bounds__(256) void k_proj(
    const float* __restrict__ ys, const float* __restrict__ WP,
    const float* __restrict__ b_out, float* __restrict__ out)
{
    __shared__ float yl[4 * 516];
    const int t = threadIdx.x;
    const size_t base = (size_t)blockIdx.x * 4 * 512;
#pragma unroll
    for (int i = 0; i < 8; ++i) {
        int q = t + 256 * i;
        yl[(q >> 9) * 516 + (q & 511)] = ys[base + q];
    }
    __syncthreads();
    const int row = t >> 6, j = t & 63;
    const float* yr = yl + row * 516;
    float acc = b_out[j];
    for (int k4 = 0; k4 < 128; ++k4) {
        float4 wv = *(const float4*)(WP + k4 * 256 + j * 4);
        float4 yv = *(const float4*)(yr + k4 * 4);
        acc += wv.x * yv.x + wv.y * yv.y + wv.z * yv.z + wv.w * yv.w;
    }
    float m = acc;
#pragma unroll
    for (int d = 1; d < 64; d <<= 1) m = fmaxf(m, __shfl_xor(m, d));
    float p = __expf(acc - m);
    float ssum = p;
#pragma unroll
    for (int d = 1; d < 64; d <<= 1) ssum += __shfl_xor(ssum, d);
    out[(size_t)blockIdx.x * 256 + t] = acc - m - __logf(ssum);
}

__global__ void k_signal(float* out, float v) { out[0] = v; }

// ---------------------------------------------------------------------------
extern "C" void kernel_launch(void* const* d_in, const int* in_sizes, int n_in,
                              void* d_out, int out_size, void* d_ws, size_t ws_size,
                              hipStream_t stream)
{
    const int*   char_sentence = (const int*)d_in[0];
    const int*   sentence      = (const int*)d_in[1];
    const float* char_emb      = (const float*)d_in[2];
    const float* word_emb      = (const float*)d_in[3];
    const float* Wih_c         = (const float*)d_in[4];
    const float* Whh_c         = (const float*)d_in[5];
    const float* bih_c         = (const float*)d_in[6];
    const float* bhh_c         = (const float*)d_in[7];
    const float* Wih_w         = (const float*)d_in[8];
    const float* Whh_w         = (const float*)d_in[9];
    const float* bih_w         = (const float*)d_in[10];
    const float* bhh_w         = (const float*)d_in[11];
    const float* W_out         = (const float*)d_in[12];
    const float* b_out         = (const float*)d_in[13];
    float* out = (float*)d_out;
    char* ws = (char*)d_ws;

    // ws layout (all f32 now)
    float* X      = (float*)(ws);                        // 8192*320*4 = 10,485,760
    float* ys     = (float*)(ws + 10485760);             // 8192*512*4 = 16,777,216
    float* h_char = (float*)(ws + 27262976);             // 8192*64*4  =  2,097,152
    u64t*  Hpub   = (u64t*)(ws + 29360128);              // 2*512*8    =      8,192
    float* WP     = (float*)(ws + 29368320);             // 64*512*4   =    131,072
    const size_t need = 29368320 + 131072;
    if (ws_size < need) {
        k_signal<<<1, 1, 0, stream>>>(out, (float)(ws_size >> 20));
        return;
    }

    k_char_lstm<<<512, 256, 0, stream>>>(char_sentence, char_emb, Wih_c, Whh_c, bih_c, bhh_c, h_char, 16);
    k_build_x<<<8192, 320, 0, stream>>>(sentence, word_emb, h_char, X);
    k_pack_wout<<<128, 256, 0, stream>>>(W_out, WP);
    hipMemsetAsync(Hpub, 0, 8192, stream);  // reset both tag buffers every launch
    k_word_lstm<<<64, 256, 0, stream>>>(Whh_w, Wih_w, X, bih_w, bhh_w, Hpub, ys);
    k_proj<<<2048, 256, 0, stream>>>(ys, WP, b_out, out);
}